// Round 13
// baseline (1882.346 us; speedup 1.0000x reference)
//
#include <hip/hip_runtime.h>
#include <cstdint>
#include <cstddef>

#define BB 128
#define TT 512
#define DD 100
#define HH 100
#define NG 400   // 4*H
#define LL 25
#define TS 32    // scan tile (steps per burst)
#define NTILE 16
#define F_LOG2E 1.44269504088896340736f
#define F_LN2   0.69314718055994530942f

typedef __decltype(__builtin_amdgcn_cvt_pkrtz(0.f, 0.f)) h2_t;
typedef _Float16 v8h __attribute__((ext_vector_type(8)));
typedef float v4f __attribute__((ext_vector_type(4)));

__device__ __forceinline__ h2_t bc_h2(unsigned int u) {
  return __builtin_bit_cast(h2_t, u);
}
__device__ __forceinline__ unsigned int pk(float x, float y) {
  return __builtin_bit_cast(unsigned int, __builtin_amdgcn_cvt_pkrtz(x, y));
}

__device__ __forceinline__ float fdot2(h2_t a, h2_t b, float c) {
#if __has_builtin(__builtin_amdgcn_fdot2)
  return __builtin_amdgcn_fdot2(a, b, c, false);
#else
  return c + (float)a[0] * (float)b[0] + (float)a[1] * (float)b[1];
#endif
}

__device__ __forceinline__ float fexp2(float x) { return __builtin_amdgcn_exp2f(x); }
__device__ __forceinline__ float flog2(float x) { return __builtin_amdgcn_logf(x); }
__device__ __forceinline__ float frcp(float x)  { return __builtin_amdgcn_rcpf(x); }

__device__ __forceinline__ float tanh_f(float x) {
  float e = fexp2(2.f * F_LOG2E * x);
  return 1.f - 2.f * frcp(e + 1.f);
}

template <int CTRL>
__device__ __forceinline__ float qadd(float v) {
#if __has_builtin(__builtin_amdgcn_mov_dpp)
  int m = __builtin_amdgcn_mov_dpp(__builtin_bit_cast(int, v), CTRL, 0xF, 0xF, true);
  return v + __builtin_bit_cast(float, m);
#else
  int x = (CTRL == 177) ? 1 : 2;
  return v + __shfl_xor(v, x);
#endif
}

template <int LANE>
__device__ __forceinline__ float qbcast(float v) {
#if __has_builtin(__builtin_amdgcn_mov_dpp)
  int m = __builtin_amdgcn_mov_dpp(__builtin_bit_cast(int, v), LANE * 0x55, 0xF, 0xF, true);
  return __builtin_bit_cast(float, m);
#else
  return __shfl(v, (threadIdx.x & 63 & ~3) + LANE);
#endif
}

__device__ __forceinline__ float rfl(float v) {
  return __builtin_bit_cast(float,
      __builtin_amdgcn_readfirstlane(__builtin_bit_cast(int, v)));
}

__device__ __forceinline__ void wave_fence() {
#if __has_builtin(__builtin_amdgcn_wave_barrier)
  __builtin_amdgcn_wave_barrier();
#endif
}

// LDS-visibility-only barrier (vmcnt left free): imm 0xC07F.
__device__ __forceinline__ void lds_barrier() {
  __builtin_amdgcn_s_waitcnt(0xC07F);
  __builtin_amdgcn_s_barrier();
}

// ---------------------------------------------------------------------------
// SINGLE-KERNEL BiLSTM-CRF. One block per BATCH ELEMENT (128 blocks), 960
// threads = 15 waves:
//   tid 0..447    : dir-0 scan group (400 unit lanes; 7 waves do MFMA bursts,
//                   416 lanes stage x)
//   tid 448..895  : dir-1 scan group (same)
//   tid 896..959  : shared emission wave: lane<25 = dir0 label, 25..49 = dir1
//                   label; each computes the FULL 100-dot w_tag·h(t-1) and
//                   accumulates em_f+em_b (f16) into em_lds (disjoint-step
//                   writes per slot, race-free by barrier ordering).
// After the 512-step scan: CRF runs IN-BLOCK (em reads are ds_reads — no
// cross-XCD traffic, no kernel boundary): wave0=alpha fwd(0..255),
// wave7=beta bwd(511..256), wave14=gold; lse-combine; atomicAdd to out.
// ---------------------------------------------------------------------------
__global__ __launch_bounds__(960, 1) void bilstm_crf(
    const int* __restrict__ tok, const float* __restrict__ emb,
    const float* __restrict__ w_ih_f, const float* __restrict__ w_ih_b,
    const float* __restrict__ b_ih_f, const float* __restrict__ b_hh_f,
    const float* __restrict__ b_ih_b, const float* __restrict__ b_hh_b,
    const float* __restrict__ w_hh_f, const float* __restrict__ w_hh_b,
    const float* __restrict__ w_tag, const float* __restrict__ b_tag,
    const int* __restrict__ tags, const int* __restrict__ lengths,
    const float* __restrict__ trans,
    const float* __restrict__ startt, const float* __restrict__ endt,
    float* __restrict__ out)
{
  const int tid = threadIdx.x;
  const int b   = blockIdx.x;

  __shared__ __align__(16) unsigned short gin_lds[2][TS * 400]; // 51.2 KB
  __shared__ __align__(16) unsigned int xlds[2][TS * 68];       // 17.4 KB
  __shared__ __align__(16) unsigned int hls[2][2][52];          // 0.83 KB
  __shared__ __align__(16) __fp16 em_lds[512 * 26];             // 26.6 KB
  __shared__ __align__(16) float As[2][32];
  __shared__ float abf[32], abb[32];
  __shared__ float gdv;

  const bool is_em = tid >= 896;
  const int dir = is_em ? 0 : (tid >= 448);       // scan-group dir
  const int u   = is_em ? 0 : (tid - (dir ? 448 : 0));

  const float* w_hh = dir ? w_hh_b : w_hh_f;
  const float* w_ih = dir ? w_ih_b : w_ih_f;
  const float* b_ih = dir ? b_ih_b : b_ih_f;
  const float* b_hh = dir ? b_hh_b : b_hh_f;

  // ---- LDS init ----
  {
    unsigned int* emu = (unsigned int*)em_lds;
    for (int i = tid; i < 512 * 26 / 2; i += 960) emu[i] = 0u;
    if (tid < 52) {
      hls[0][0][tid] = 0u; hls[0][1][tid] = 0u;
      hls[1][0][tid] = 0u; hls[1][1][tid] = 0u;
    }
    if (tid >= 25 && tid < 32) { As[0][tid] = 0.f; As[1][tid] = 0.f; }
    for (int i = tid; i < 2 * TS * 18; i += 960) {
      int dd = i / (TS * 18);
      int r  = (i - dd * TS * 18) / 18;
      int q  = i - dd * TS * 18 - r * 18;
      xlds[dd][r * 68 + 50 + q] = 0u;
    }
  }

  // ---- burst lane mapping (scan groups only) ----
  const int wv   = u >> 6;              // 0..6
  const int lane = u & 63;
  const int l16  = lane & 15;
  const int quad = lane >> 4;
  const int c0b  = (25 * wv) / 7;
  const int c1b  = (25 * (wv + 1)) / 7;
  const int ncol = c1b - c0b;           // 3 or 4

  // one-time B fragments (w_ih) in registers
  v8h bfr[4][4];
  int pcol[4];
  if (!is_em) {
#pragma unroll
    for (int ci = 0; ci < 4; ++ci) {
      const int cc = (ci < ncol) ? (c0b + ci) : c0b;
      const int n  = 16 * cc + l16;
      const float* wr = w_ih + (size_t)n * DD;
#pragma unroll
      for (int f = 0; f < 3; ++f) {
        const float* wp = wr + f * 32 + quad * 8;
        float4 va = *(const float4*)(wp);
        float4 vb = *(const float4*)(wp + 4);
        uint4 uu;
        uu.x = pk(va.x, va.y); uu.y = pk(va.z, va.w);
        uu.z = pk(vb.x, vb.y); uu.w = pk(vb.z, vb.w);
        bfr[ci][f] = __builtin_bit_cast(v8h, uu);
      }
      {
        uint4 uu = {0u, 0u, 0u, 0u};
        if (quad == 0) {
          float4 va = *(const float4*)(wr + 96);
          uu.x = pk(va.x, va.y); uu.y = pk(va.z, va.w);
        }
        bfr[ci][3] = __builtin_bit_cast(v8h, uu);
      }
      const int qn = (n * 41) >> 12;
      pcol[ci] = ((n - 100 * qn) << 2) + qn;
    }
  }

  // ---- scan unit-lane state ----
  const bool uact = !is_em && (u < 400);
  const int j = u >> 2;
  const int s = u & 3;
  const int od = 12 * s;
  const int nnv = (s == 3) ? 14 : 12;

  h2_t wA[14], wB[14], wC[14], wD[14];
  float bias = 0.f;
  if (uact) {
#pragma unroll
    for (int d = 0; d < 14; ++d) {
      int dd = (d < nnv) ? (od + d) : 0;
      const float* r0 = w_hh + (size_t)(0 * 100 + j) * HH + 2 * dd;
      const float* r1 = w_hh + (size_t)(1 * 100 + j) * HH + 2 * dd;
      const float* r2 = w_hh + (size_t)(2 * 100 + j) * HH + 2 * dd;
      const float* r3 = w_hh + (size_t)(3 * 100 + j) * HH + 2 * dd;
      h2_t z = __builtin_amdgcn_cvt_pkrtz(0.f, 0.f);
      wA[d] = (d < nnv) ? __builtin_amdgcn_cvt_pkrtz(r0[0], r0[1]) : z;
      wB[d] = (d < nnv) ? __builtin_amdgcn_cvt_pkrtz(r1[0], r1[1]) : z;
      wC[d] = (d < nnv) ? __builtin_amdgcn_cvt_pkrtz(r2[0], r2[1]) : z;
      wD[d] = (d < nnv) ? __builtin_amdgcn_cvt_pkrtz(r3[0], r3[1]) : z;
    }
    bias = b_ih[s * 100 + j] + b_hh[s * 100 + j];
  }
  const float kk2 = (s == 2) ? (2.f * F_LOG2E) : (-F_LOG2E);
  const float cA  = (s == 2) ? -2.f : 1.f;
  const float cB  = (s == 2) ? 1.f : 0.f;

  // ---- emission lane state (wave 14) ----
  const int el = tid - 896;
  const bool eact = is_em && (el < 50);
  const int edir = (el >= 25) ? 1 : 0;
  const int l = eact ? (edir ? (el - 25) : el) : 0;
  h2_t wt[50];
  float bt = 0.f;
  if (eact) {
    const float* wr = w_tag + (size_t)l * 200 + edir * 100;
#pragma unroll
    for (int d = 0; d < 50; ++d)
      wt[d] = __builtin_amdgcn_cvt_pkrtz(wr[2 * d], wr[2 * d + 1]);
    if (edir == 0) bt = b_tag[l];
  }
  int eslot = edir ? (TT - 1) : 0;
  const int estp = edir ? -1 : 1;

  // ---- x staging mapping ----
  const int tprow = u / 13;
  const int tps   = u - 13 * tprow;
  const bool tp_act = !is_em && (u < 416);

  float4 xa = {0, 0, 0, 0}, xb = {0, 0, 0, 0};
  if (tp_act) {
    int tt = dir ? (TT - 1 - tprow) : tprow;
    int tk = tok[b * TT + tt];
    const float* xp = emb + (size_t)tk * DD + 8 * tps;
    xa = *(const float4*)xp;
    if (tps < 12) xb = *(const float4*)(xp + 4);
  }

  float c = 0.f;
  unsigned short gnext = 0;
  int grow = 0;

#define SDOT(d, hh) \
  p0 = fdot2(wA[d], bc_h2(hh), p0); p1 = fdot2(wB[d], bc_h2(hh), p1); \
  p2 = fdot2(wC[d], bc_h2(hh), p2); p3 = fdot2(wD[d], bc_h2(hh), p3);
#define EDOT(d, hh) { h2_t h = bc_h2(hh); \
  if ((d & 3) == 0) a0 = fdot2(wt[d], h, a0); \
  else if ((d & 3) == 1) a1 = fdot2(wt[d], h, a1); \
  else if ((d & 3) == 2) a2 = fdot2(wt[d], h, a2); \
  else a3 = fdot2(wt[d], h, a3); }

#define SCAN_STEP(RB, WB, TVNZ)                                            \
  {                                                                        \
    if (uact) {                                                            \
      unsigned short gcurr = gnext;                                        \
      int nr = (grow < TS - 1) ? grow + 1 : TS - 1;                        \
      gnext = gin_lds[dir][nr * 400 + u];                                  \
      grow = nr;                                                           \
      const unsigned int* hp = hls[dir][RB] + od;                          \
      uint4 u0 = *((const uint4*)hp);                                      \
      uint4 u1 = *((const uint4*)(hp + 4));                                \
      uint4 u2 = *((const uint4*)(hp + 8));                                \
      uint2 u3 = *((const uint2*)(hp + 12));                               \
      float p0, p1, p2, p3;                                                \
      p0 = fdot2(wA[0], bc_h2(u0.x), 0.f);                                 \
      p1 = fdot2(wB[0], bc_h2(u0.x), 0.f);                                 \
      p2 = fdot2(wC[0], bc_h2(u0.x), 0.f);                                 \
      p3 = fdot2(wD[0], bc_h2(u0.x), 0.f);                                 \
      SDOT(1, u0.y)  SDOT(2, u0.z)  SDOT(3, u0.w)                          \
      SDOT(4, u1.x)  SDOT(5, u1.y)  SDOT(6, u1.z)  SDOT(7, u1.w)           \
      SDOT(8, u2.x)  SDOT(9, u2.y)  SDOT(10, u2.z) SDOT(11, u2.w)          \
      SDOT(12, u3.x) SDOT(13, u3.y)                                        \
      p0 = qadd<78>(qadd<177>(p0));                                        \
      p1 = qadd<78>(qadd<177>(p1));                                        \
      p2 = qadd<78>(qadd<177>(p2));                                        \
      p3 = qadd<78>(qadd<177>(p3));                                        \
      float psel = (s == 0) ? p0 : (s == 1) ? p1 : (s == 2) ? p2 : p3;     \
      float gate = psel + bias + (float)__builtin_bit_cast(__fp16, gcurr); \
      float y  = fexp2(kk2 * gate);                                        \
      float rr = frcp(1.f + y);                                            \
      float actv = fmaf(cA, rr, cB);                                       \
      float iv = qbcast<0>(actv);                                          \
      float fv = qbcast<1>(actv);                                          \
      float gv = qbcast<2>(actv);                                          \
      float ov = qbcast<3>(actv);                                          \
      c = fmaf(fv, c, iv * gv);                                            \
      float hvv = ov * tanh_f(c);                                          \
      if (s == 0) ((__fp16*)hls[dir][WB])[j] = (__fp16)hvv;                \
    } else if (eact && (TVNZ)) {                                           \
      const unsigned int* hb = hls[edir][RB];                              \
      uint4 e0 = ((const uint4*)hb)[0];                                    \
      uint4 e1 = ((const uint4*)hb)[1];                                    \
      uint4 e2 = ((const uint4*)hb)[2];                                    \
      uint4 e3 = ((const uint4*)hb)[3];                                    \
      uint4 e4 = ((const uint4*)hb)[4];                                    \
      uint4 e5 = ((const uint4*)hb)[5];                                    \
      uint4 e6 = ((const uint4*)hb)[6];                                    \
      uint4 e7 = ((const uint4*)hb)[7];                                    \
      uint4 e8 = ((const uint4*)hb)[8];                                    \
      uint4 e9 = ((const uint4*)hb)[9];                                    \
      uint4 eA = ((const uint4*)hb)[10];                                   \
      uint4 eB = ((const uint4*)hb)[11];                                   \
      uint2 eC = *((const uint2*)(hb + 48));                               \
      float a0, a1, a2, a3;                                                \
      a0 = fdot2(wt[0], bc_h2(e0.x), 0.f);                                 \
      a1 = fdot2(wt[1], bc_h2(e0.y), 0.f);                                 \
      a2 = fdot2(wt[2], bc_h2(e0.z), 0.f);                                 \
      a3 = fdot2(wt[3], bc_h2(e0.w), 0.f);                                 \
      EDOT(4, e1.x)  EDOT(5, e1.y)  EDOT(6, e1.z)  EDOT(7, e1.w)           \
      EDOT(8, e2.x)  EDOT(9, e2.y)  EDOT(10, e2.z) EDOT(11, e2.w)          \
      EDOT(12, e3.x) EDOT(13, e3.y) EDOT(14, e3.z) EDOT(15, e3.w)          \
      EDOT(16, e4.x) EDOT(17, e4.y) EDOT(18, e4.z) EDOT(19, e4.w)          \
      EDOT(20, e5.x) EDOT(21, e5.y) EDOT(22, e5.z) EDOT(23, e5.w)          \
      EDOT(24, e6.x) EDOT(25, e6.y) EDOT(26, e6.z) EDOT(27, e6.w)          \
      EDOT(28, e7.x) EDOT(29, e7.y) EDOT(30, e7.z) EDOT(31, e7.w)          \
      EDOT(32, e8.x) EDOT(33, e8.y) EDOT(34, e8.z) EDOT(35, e8.w)          \
      EDOT(36, e9.x) EDOT(37, e9.y) EDOT(38, e9.z) EDOT(39, e9.w)          \
      EDOT(40, eA.x) EDOT(41, eA.y) EDOT(42, eA.z) EDOT(43, eA.w)          \
      EDOT(44, eB.x) EDOT(45, eB.y) EDOT(46, eB.z) EDOT(47, eB.w)          \
      EDOT(48, eC.x) EDOT(49, eC.y)                                        \
      float ss = ((a0 + a1) + (a2 + a3)) + bt;                             \
      __fp16* ep = em_lds + eslot * 26 + l;                                \
      *ep = (__fp16)((float)*ep + ss);                                     \
      eslot += estp;                                                       \
    }                                                                      \
    lds_barrier();                                                         \
  }

  __syncthreads();  // LDS init complete

  for (int T = 0; T < NTILE; ++T) {
    // write prefetched x regs into xlds
    if (tp_act) {
      unsigned int* xr = xlds[dir] + tprow * 68 + 4 * tps;
      if (tps < 12) {
        uint4 uu;
        uu.x = pk(xa.x, xa.y); uu.y = pk(xa.z, xa.w);
        uu.z = pk(xb.x, xb.y); uu.w = pk(xb.z, xb.w);
        *(uint4*)xr = uu;
      } else {
        xr[0] = pk(xa.x, xa.y);
        xr[1] = pk(xa.z, xa.w);
      }
    }
    __syncthreads();

    // BURST (scan groups; emission wave idles)
    if (!is_em) {
      v8h af[2][4];
#pragma unroll
      for (int rg = 0; rg < 2; ++rg)
#pragma unroll
        for (int f = 0; f < 4; ++f)
          af[rg][f] = __builtin_bit_cast(v8h,
              *(const uint4*)(xlds[dir] + (rg * 16 + l16) * 68 + f * 16 + quad * 4));

      if (tp_act && T + 1 < NTILE) {
        int ii = (T + 1) * TS + tprow;
        int tt = dir ? (TT - 1 - ii) : ii;
        int tk = tok[b * TT + tt];
        const float* xp = emb + (size_t)tk * DD + 8 * tps;
        xa = *(const float4*)xp;
        if (tps < 12) xb = *(const float4*)(xp + 4);
      }

      __fp16* gout = (__fp16*)gin_lds[dir];
#pragma unroll
      for (int ci = 0; ci < 4; ++ci) {
        if (ci >= ncol) break;
        const int p = pcol[ci];
#pragma unroll
        for (int rg = 0; rg < 2; ++rg) {
          v4f acc = {0.f, 0.f, 0.f, 0.f};
          acc = __builtin_amdgcn_mfma_f32_16x16x32_f16(af[rg][0], bfr[ci][0], acc, 0, 0, 0);
          acc = __builtin_amdgcn_mfma_f32_16x16x32_f16(af[rg][1], bfr[ci][1], acc, 0, 0, 0);
          acc = __builtin_amdgcn_mfma_f32_16x16x32_f16(af[rg][2], bfr[ci][2], acc, 0, 0, 0);
          acc = __builtin_amdgcn_mfma_f32_16x16x32_f16(af[rg][3], bfr[ci][3], acc, 0, 0, 0);
          const int rowb = rg * 16 + quad * 4;
#pragma unroll
          for (int r = 0; r < 4; ++r)
            gout[(rowb + r) * 400 + p] = (__fp16)acc[r];
        }
      }
    }
    __syncthreads();
    if (uact) { grow = 0; gnext = gin_lds[dir][u]; }

    SCAN_STEP(0, 1, (T > 0))
    SCAN_STEP(1, 0, true)
    for (int it = 1; it < TS / 2; ++it) {
      SCAN_STEP(0, 1, true)
      SCAN_STEP(1, 0, true)
    }
  }
#undef SCAN_STEP
#undef SDOT

  // epilogue emission: last h of each dir sits in hls[edir][0]
  if (eact) {
    const unsigned int* hb = hls[edir][0];
    uint4 e0 = ((const uint4*)hb)[0];
    uint4 e1 = ((const uint4*)hb)[1];
    uint4 e2 = ((const uint4*)hb)[2];
    uint4 e3 = ((const uint4*)hb)[3];
    uint4 e4 = ((const uint4*)hb)[4];
    uint4 e5 = ((const uint4*)hb)[5];
    uint4 e6 = ((const uint4*)hb)[6];
    uint4 e7 = ((const uint4*)hb)[7];
    uint4 e8 = ((const uint4*)hb)[8];
    uint4 e9 = ((const uint4*)hb)[9];
    uint4 eA = ((const uint4*)hb)[10];
    uint4 eB = ((const uint4*)hb)[11];
    uint2 eC = *((const uint2*)(hb + 48));
    float a0, a1, a2, a3;
    a0 = fdot2(wt[0], bc_h2(e0.x), 0.f);
    a1 = fdot2(wt[1], bc_h2(e0.y), 0.f);
    a2 = fdot2(wt[2], bc_h2(e0.z), 0.f);
    a3 = fdot2(wt[3], bc_h2(e0.w), 0.f);
    EDOT(4, e1.x)  EDOT(5, e1.y)  EDOT(6, e1.z)  EDOT(7, e1.w)
    EDOT(8, e2.x)  EDOT(9, e2.y)  EDOT(10, e2.z) EDOT(11, e2.w)
    EDOT(12, e3.x) EDOT(13, e3.y) EDOT(14, e3.z) EDOT(15, e3.w)
    EDOT(16, e4.x) EDOT(17, e4.y) EDOT(18, e4.z) EDOT(19, e4.w)
    EDOT(20, e5.x) EDOT(21, e5.y) EDOT(22, e5.z) EDOT(23, e5.w)
    EDOT(24, e6.x) EDOT(25, e6.y) EDOT(26, e6.z) EDOT(27, e6.w)
    EDOT(28, e7.x) EDOT(29, e7.y) EDOT(30, e7.z) EDOT(31, e7.w)
    EDOT(32, e8.x) EDOT(33, e8.y) EDOT(34, e8.z) EDOT(35, e8.w)
    EDOT(36, e9.x) EDOT(37, e9.y) EDOT(38, e9.z) EDOT(39, e9.w)
    EDOT(40, eA.x) EDOT(41, eA.y) EDOT(42, eA.z) EDOT(43, eA.w)
    EDOT(44, eB.x) EDOT(45, eB.y) EDOT(46, eB.z) EDOT(47, eB.w)
    EDOT(48, eC.x) EDOT(49, eC.y)
    float ss = ((a0 + a1) + (a2 + a3)) + bt;
    int fslot = edir ? 0 : (TT - 1);
    __fp16* ep = em_lds + fslot * 26 + l;
    *ep = (__fp16)((float)*ep + ss);
  }
#undef EDOT
  __syncthreads();

  // =========================== CRF PHASE ===========================
  const int wvg = tid >> 6;   // wave index 0..14
  if (wvg == 0 || wvg == 7) {
    const int side = (wvg == 7);
    const int cl = tid & 63;
    const int jj = (cl < LL) ? cl : 0;
    float* Aw = As[side];
    const float4* Ap = (const float4*)Aw;

    float E[28];
#pragma unroll
    for (int i = 0; i < LL; ++i) {
      float tv = (side == 0 ? trans[i * LL + jj] : trans[jj * LL + i]);
      E[i] = fexp2(tv * F_LOG2E);
    }
    E[25] = 0.f; E[26] = 0.f; E[27] = 0.f;

#define LSE_STEP(vin, aout)                                                \
    {                                                                      \
      float sh = rfl(vin);                                                 \
      C += sh;                                                             \
      float A = fexp2((vin) - sh);                                         \
      if (cl < LL) Aw[cl] = A;                                             \
      wave_fence();                                                        \
      float4 q0 = Ap[0], q1 = Ap[1], q2 = Ap[2], q3 = Ap[3];               \
      float4 q4 = Ap[4], q5 = Ap[5], q6 = Ap[6];                           \
      float s0, s1, s2, s3;                                                \
      s0 = q0.x * E[0];  s1 = q0.y * E[1];                                 \
      s2 = q0.z * E[2];  s3 = q0.w * E[3];                                 \
      s0 = fmaf(q1.x, E[4], s0);  s1 = fmaf(q1.y, E[5], s1);               \
      s2 = fmaf(q1.z, E[6], s2);  s3 = fmaf(q1.w, E[7], s3);               \
      s0 = fmaf(q2.x, E[8], s0);  s1 = fmaf(q2.y, E[9], s1);               \
      s2 = fmaf(q2.z, E[10], s2); s3 = fmaf(q2.w, E[11], s3);              \
      s0 = fmaf(q3.x, E[12], s0); s1 = fmaf(q3.y, E[13], s1);              \
      s2 = fmaf(q3.z, E[14], s2); s3 = fmaf(q3.w, E[15], s3);              \
      s0 = fmaf(q4.x, E[16], s0); s1 = fmaf(q4.y, E[17], s1);              \
      s2 = fmaf(q4.z, E[18], s2); s3 = fmaf(q4.w, E[19], s3);              \
      s0 = fmaf(q5.x, E[20], s0); s1 = fmaf(q5.y, E[21], s1);              \
      s2 = fmaf(q5.z, E[22], s2); s3 = fmaf(q5.w, E[23], s3);              \
      s0 = fmaf(q6.x, E[24], s0); s1 = fmaf(q6.y, E[25], s1);              \
      s2 = fmaf(q6.z, E[26], s2); s3 = fmaf(q6.w, E[27], s3);              \
      aout = flog2((s0 + s1) + (s2 + s3));                                 \
    }

    float a, C = 0.f;
    if (side == 0) {
      a = (startt[jj] + (float)em_lds[jj]) * F_LOG2E;
      float emn = (float)em_lds[26 + jj];
      for (int t = 1; t < 256; ++t) {
        float em2 = emn * F_LOG2E;
        int tn = (t + 1 < 256) ? (t + 1) : 255;
        emn = (float)em_lds[tn * 26 + jj];
        float nx;
        LSE_STEP(a, nx)
        a = nx + em2;
      }
      if (cl < LL) abf[cl] = a + C;
    } else {
      a = endt[jj] * F_LOG2E;
      float emn = (float)em_lds[(TT - 1) * 26 + jj];
      for (int stpi = 0; stpi < 256; ++stpi) {
        float em2 = emn * F_LOG2E;
        int t1n = (stpi + 1 < 256) ? (TT - 2 - stpi) : 256;
        emn = (float)em_lds[t1n * 26 + jj];
        float v = a + em2;
        LSE_STEP(v, a)
      }
      if (cl < LL) abb[cl] = a + C;
    }
#undef LSE_STEP
  } else if (wvg == 14) {
    const int cl = tid & 63;
    const int len = lengths[b];
    float acc = 0.f;
#pragma unroll
    for (int k = 0; k < 8; ++k) {
      int t = k * 64 + cl;
      int tg = tags[b * TT + t];
      float e = (float)em_lds[t * 26 + tg];
      float term;
      if (t == 0) term = startt[tg] + e;
      else        term = trans[tags[b * TT + t - 1] * LL + tg] + e;
      if (t == len - 1) term += endt[tg];
      if (t < len) acc += term;
    }
    for (int o = 32; o > 0; o >>= 1) acc += __shfl_down(acc, o);
    if (cl == 0) gdv = acc;
  }
  __syncthreads();

  if (tid < 64) {
    float v = (tid < LL) ? (abf[tid] + abb[tid]) : -1e30f;
    float m = v;
    for (int o = 32; o > 0; o >>= 1) m = fmaxf(m, __shfl_down(m, o));
    m = rfl(m);
    float e = (tid < LL) ? fexp2(v - m) : 0.f;
    for (int o = 32; o > 0; o >>= 1) e += __shfl_down(e, o);
    if (tid == 0)
      atomicAdd(out, (m + flog2(e)) * F_LN2 - gdv);
  }
}

extern "C" void kernel_launch(void* const* d_in, const int* in_sizes, int n_in,
                              void* d_out, int out_size, void* d_ws, size_t ws_size,
                              hipStream_t stream) {
  const int*   tok   = (const int*)d_in[0];
  const int*   tags  = (const int*)d_in[1];
  const int*   lens  = (const int*)d_in[2];
  const float* emb   = (const float*)d_in[3];
  const float* wif   = (const float*)d_in[4];
  const float* whf   = (const float*)d_in[5];
  const float* bif   = (const float*)d_in[6];
  const float* bhf   = (const float*)d_in[7];
  const float* wib   = (const float*)d_in[8];
  const float* whb   = (const float*)d_in[9];
  const float* bib   = (const float*)d_in[10];
  const float* bhb   = (const float*)d_in[11];
  const float* wtag  = (const float*)d_in[12];
  const float* btag  = (const float*)d_in[13];
  const float* trans = (const float*)d_in[14];
  const float* st    = (const float*)d_in[15];
  const float* en    = (const float*)d_in[16];

  hipMemsetAsync(d_out, 0, sizeof(float), stream);

  bilstm_crf<<<128, 960, 0, stream>>>(tok, emb, wif, wib, bif, bhf, bib, bhb,
                                      whf, whb, wtag, btag, tags, lens,
                                      trans, st, en, (float*)d_out);
}

// Round 14
// 424.388 us; speedup vs baseline: 4.4354x; 4.4354x over previous
//
#include <hip/hip_runtime.h>
#include <cstdint>
#include <cstddef>

#define BB 128
#define TT 512
#define DD 100
#define HH 100
#define NG 400   // 4*H
#define LL 25
#define TS 32    // scan tile (steps per burst)
#define NTILE 16
#define F_LOG2E 1.44269504088896340736f
#define F_LN2   0.69314718055994530942f

typedef __decltype(__builtin_amdgcn_cvt_pkrtz(0.f, 0.f)) h2_t;
typedef _Float16 v8h __attribute__((ext_vector_type(8)));
typedef float v4f __attribute__((ext_vector_type(4)));

__device__ __forceinline__ h2_t bc_h2(unsigned int u) {
  return __builtin_bit_cast(h2_t, u);
}
__device__ __forceinline__ unsigned int pk(float x, float y) {
  return __builtin_bit_cast(unsigned int, __builtin_amdgcn_cvt_pkrtz(x, y));
}

__device__ __forceinline__ float fdot2(h2_t a, h2_t b, float c) {
#if __has_builtin(__builtin_amdgcn_fdot2)
  return __builtin_amdgcn_fdot2(a, b, c, false);
#else
  return c + (float)a[0] * (float)b[0] + (float)a[1] * (float)b[1];
#endif
}

__device__ __forceinline__ float fexp2(float x) { return __builtin_amdgcn_exp2f(x); }
__device__ __forceinline__ float flog2(float x) { return __builtin_amdgcn_logf(x); }
__device__ __forceinline__ float frcp(float x)  { return __builtin_amdgcn_rcpf(x); }

__device__ __forceinline__ float sigmoid_f(float x) {
  return frcp(1.f + fexp2(-F_LOG2E * x));
}
__device__ __forceinline__ float tanh_f(float x) {
  float e = fexp2(2.f * F_LOG2E * x);
  return 1.f - 2.f * frcp(e + 1.f);
}

template <int CTRL>
__device__ __forceinline__ float qadd(float v) {
#if __has_builtin(__builtin_amdgcn_mov_dpp)
  int m = __builtin_amdgcn_mov_dpp(__builtin_bit_cast(int, v), CTRL, 0xF, 0xF, true);
  return v + __builtin_bit_cast(float, m);
#else
  int x = (CTRL == 177) ? 1 : 2;
  return v + __shfl_xor(v, x);
#endif
}

template <int LANE>
__device__ __forceinline__ float qbcast(float v) {
#if __has_builtin(__builtin_amdgcn_mov_dpp)
  int m = __builtin_amdgcn_mov_dpp(__builtin_bit_cast(int, v), LANE * 0x55, 0xF, 0xF, true);
  return __builtin_bit_cast(float, m);
#else
  return __shfl(v, (threadIdx.x & 63 & ~3) + LANE);
#endif
}

__device__ __forceinline__ float rfl(float v) {
  return __builtin_bit_cast(float,
      __builtin_amdgcn_readfirstlane(__builtin_bit_cast(int, v)));
}

__device__ __forceinline__ void wave_fence() {
#if __has_builtin(__builtin_amdgcn_wave_barrier)
  __builtin_amdgcn_wave_barrier();
#endif
}

// LDS-visibility-only barrier (vmcnt left free): imm 0xC07F.
__device__ __forceinline__ void lds_barrier() {
  __builtin_amdgcn_s_waitcnt(0xC07F);
  __builtin_amdgcn_s_barrier();
}

// ---------------------------------------------------------------------------
// FUSED BiLSTM + x-GEMM + emissions (v3 — best measured: 300 us).
// One block per (batch, dir), 512 thr. B-fragments of w_ih in registers;
// x tiles (32 steps) register-prefetched one tile early -> xlds. BURST:
// wave w owns 3-4 B-columns x 2 m-tiles, mfma_16x16x32_f16, store perm
// p(n)=4*(n%100)+n/100 into gin_lds. SCAN: v6 structure (depth-1 gin LDS
// prefetch, DPP quad reduce/bcast, one lgkm-only barrier per step).
// ---------------------------------------------------------------------------
__global__ __launch_bounds__(512, 2) void lstm_fused3(
    const int* __restrict__ tok, const float* __restrict__ emb,
    const float* __restrict__ w_ih_f, const float* __restrict__ w_ih_b,
    const float* __restrict__ b_ih_f, const float* __restrict__ b_hh_f,
    const float* __restrict__ b_ih_b, const float* __restrict__ b_hh_b,
    const float* __restrict__ w_hh_f, const float* __restrict__ w_hh_b,
    const float* __restrict__ w_tag, const float* __restrict__ b_tag,
    float* __restrict__ em_f, float* __restrict__ em_b)
{
  const int tid = threadIdx.x;
  const int b   = blockIdx.x & 127;
  const int dir = blockIdx.x >> 7;
  const float* w_hh = dir ? w_hh_b : w_hh_f;
  const float* w_ih = dir ? w_ih_b : w_ih_f;
  const float* b_ih = dir ? b_ih_b : b_ih_f;
  const float* b_hh = dir ? b_hh_b : b_hh_f;

  __shared__ __align__(16) unsigned short gin_lds[TS * 400];   // 25.6 KB
  __shared__ __align__(16) unsigned int xlds[TS * 68];         // 8.7 KB
  __shared__ __align__(16) unsigned int hls0[52];
  __shared__ __align__(16) unsigned int hls1[52];

  // burst lane mapping
  const int wv   = tid >> 6;
  const int lane = tid & 63;
  const int l16  = lane & 15;
  const int quad = lane >> 4;
  const int c0b  = (25 * wv) >> 3;
  const int c1b  = (25 * (wv + 1)) >> 3;
  const int ncol = c1b - c0b;   // 3 or 4

  // ---- one-time: B fragments from global w_ih into registers ----
  v8h bfr[4][4];
  int pcol[4];
#pragma unroll
  for (int ci = 0; ci < 4; ++ci) {
    const int cc = (ci < ncol) ? (c0b + ci) : c0b;
    const int n  = 16 * cc + l16;
    const float* wr = w_ih + (size_t)n * DD;
#pragma unroll
    for (int f = 0; f < 3; ++f) {
      const float* wp = wr + f * 32 + quad * 8;
      float4 va = *(const float4*)(wp);
      float4 vb = *(const float4*)(wp + 4);
      uint4 u;
      u.x = pk(va.x, va.y); u.y = pk(va.z, va.w);
      u.z = pk(vb.x, vb.y); u.w = pk(vb.z, vb.w);
      bfr[ci][f] = __builtin_bit_cast(v8h, u);
    }
    {
      uint4 u = {0u, 0u, 0u, 0u};
      if (quad == 0) {
        float4 va = *(const float4*)(wr + 96);
        u.x = pk(va.x, va.y); u.y = pk(va.z, va.w);
      }
      bfr[ci][3] = __builtin_bit_cast(v8h, u);
    }
    const int qn = (n * 41) >> 12;            // n/100 for n<400
    pcol[ci] = ((n - 100 * qn) << 2) + qn;    // store permutation
  }

  // ---- xlds K-pad zero ----
  for (int i = tid; i < TS * 18; i += 512) {
    int row = i / 18;
    int d = i - row * 18;
    xlds[row * 68 + 50 + d] = 0u;
  }

  // ---- scan state (v6) ----
  const bool uact = tid < NG;
  const int j = tid >> 2;
  const int s = tid & 3;
  const int od = 12 * s;
  const int nnv = (s == 3) ? 14 : 12;

  h2_t wA[14], wB[14], wC[14], wD[14];
  float bias = 0.f;
  if (uact) {
#pragma unroll
    for (int d = 0; d < 14; ++d) {
      int dd = (d < nnv) ? (od + d) : 0;
      const float* r0 = w_hh + (size_t)(0 * 100 + j) * HH + 2 * dd;
      const float* r1 = w_hh + (size_t)(1 * 100 + j) * HH + 2 * dd;
      const float* r2 = w_hh + (size_t)(2 * 100 + j) * HH + 2 * dd;
      const float* r3 = w_hh + (size_t)(3 * 100 + j) * HH + 2 * dd;
      h2_t z = __builtin_amdgcn_cvt_pkrtz(0.f, 0.f);
      wA[d] = (d < nnv) ? __builtin_amdgcn_cvt_pkrtz(r0[0], r0[1]) : z;
      wB[d] = (d < nnv) ? __builtin_amdgcn_cvt_pkrtz(r1[0], r1[1]) : z;
      wC[d] = (d < nnv) ? __builtin_amdgcn_cvt_pkrtz(r2[0], r2[1]) : z;
      wD[d] = (d < nnv) ? __builtin_amdgcn_cvt_pkrtz(r3[0], r3[1]) : z;
    }
    bias = b_ih[s * 100 + j] + b_hh[s * 100 + j];
  }
  const float kk2 = (s == 2) ? (2.f * F_LOG2E) : (-F_LOG2E);
  const float cA  = (s == 2) ? -2.f : 1.f;
  const float cB  = (s == 2) ? 1.f : 0.f;

  // emission lanes: wave 7
  const int el = tid - 448;
  const bool eact = (el >= 0) && (el < 50);
  const int l  = (el >= 0) ? (el >> 1) : 0;
  const int hf = (el >= 0) ? (el & 1) : 0;
  const int eo = hf ? 24 : 0;
  const int en = hf ? 26 : 24;
  h2_t wt[26];
  float bt = 0.f;
  if (eact) {
    const float* wr = w_tag + (size_t)l * 200 + dir * 100;
#pragma unroll
    for (int d = 0; d < 26; ++d) {
      int dd = (d < en) ? (eo + d) : 0;
      h2_t z = __builtin_amdgcn_cvt_pkrtz(0.f, 0.f);
      wt[d] = (d < en) ? __builtin_amdgcn_cvt_pkrtz(wr[2 * dd], wr[2 * dd + 1]) : z;
    }
    if (dir == 0 && hf == 0) bt = b_tag[l];
  }
  float* emo = dir ? em_b : em_f;
  float* emp = emo + ((size_t)b * TT + (dir ? (TT - 1) : 0)) * LL + l;
  const ptrdiff_t estep = dir ? -(ptrdiff_t)LL : (ptrdiff_t)LL;

  if (tid < 52) { hls0[tid] = 0u; hls1[tid] = 0u; }

  // x staging mapping: thread t<416 covers (row = t/13, seg = t%13)
  const int tprow = tid / 13;
  const int tps   = tid - 13 * tprow;
  const bool tp_act = tid < 416;

  // initial x prefetch (tile 0)
  float4 xa = {0, 0, 0, 0}, xb = {0, 0, 0, 0};
  if (tp_act) {
    int ii = tprow;
    int tt = dir ? (TT - 1 - ii) : ii;
    int tk = tok[b * TT + tt];
    const float* xp = emb + (size_t)tk * DD + 8 * tps;
    xa = *(const float4*)xp;
    if (tps < 12) xb = *(const float4*)(xp + 4);
  }

  float c = 0.f;
  unsigned short gnext = 0;
  int grow = 0;

#define SDOT(d, hh) \
  p0 = fdot2(wA[d], bc_h2(hh), p0); p1 = fdot2(wB[d], bc_h2(hh), p1); \
  p2 = fdot2(wC[d], bc_h2(hh), p2); p3 = fdot2(wD[d], bc_h2(hh), p3);
#define EDOT(d, hh) { h2_t h = bc_h2(hh); \
  if ((d & 3) == 0) a0 = fdot2(wt[d], h, a0); \
  else if ((d & 3) == 1) a1 = fdot2(wt[d], h, a1); \
  else if ((d & 3) == 2) a2 = fdot2(wt[d], h, a2); \
  else a3 = fdot2(wt[d], h, a3); }

#define SCAN_STEP(HRD, HWR, TVNZ)                                          \
  {                                                                        \
    if (uact) {                                                            \
      unsigned short gcurr = gnext;                                        \
      int nr = (grow < TS - 1) ? grow + 1 : TS - 1;                        \
      gnext = gin_lds[nr * 400 + tid];                                     \
      grow = nr;                                                           \
      const unsigned int* hp = (HRD) + od;                                 \
      uint4 u0 = *((const uint4*)hp);                                      \
      uint4 u1 = *((const uint4*)(hp + 4));                                \
      uint4 u2 = *((const uint4*)(hp + 8));                                \
      uint2 u3 = *((const uint2*)(hp + 12));                               \
      float p0, p1, p2, p3;                                                \
      p0 = fdot2(wA[0], bc_h2(u0.x), 0.f);                                 \
      p1 = fdot2(wB[0], bc_h2(u0.x), 0.f);                                 \
      p2 = fdot2(wC[0], bc_h2(u0.x), 0.f);                                 \
      p3 = fdot2(wD[0], bc_h2(u0.x), 0.f);                                 \
      SDOT(1, u0.y)  SDOT(2, u0.z)  SDOT(3, u0.w)                          \
      SDOT(4, u1.x)  SDOT(5, u1.y)  SDOT(6, u1.z)  SDOT(7, u1.w)           \
      SDOT(8, u2.x)  SDOT(9, u2.y)  SDOT(10, u2.z) SDOT(11, u2.w)          \
      SDOT(12, u3.x) SDOT(13, u3.y)                                        \
      p0 = qadd<78>(qadd<177>(p0));                                        \
      p1 = qadd<78>(qadd<177>(p1));                                        \
      p2 = qadd<78>(qadd<177>(p2));                                        \
      p3 = qadd<78>(qadd<177>(p3));                                        \
      float psel = (s == 0) ? p0 : (s == 1) ? p1 : (s == 2) ? p2 : p3;     \
      float gate = psel + bias + (float)__builtin_bit_cast(__fp16, gcurr); \
      float y  = fexp2(kk2 * gate);                                        \
      float rr = frcp(1.f + y);                                            \
      float actv = fmaf(cA, rr, cB);                                       \
      float iv = qbcast<0>(actv);                                          \
      float fv = qbcast<1>(actv);                                          \
      float gv = qbcast<2>(actv);                                          \
      float ov = qbcast<3>(actv);                                          \
      c = fmaf(fv, c, iv * gv);                                            \
      float hvv = ov * tanh_f(c);                                          \
      if (s == 0) ((__fp16*)(HWR))[j] = (__fp16)hvv;                       \
    } else if (eact && (TVNZ)) {                                           \
      const unsigned int* hp = (HRD) + eo;                                 \
      uint4 e0 = *((const uint4*)hp);                                      \
      uint4 e1 = *((const uint4*)(hp + 4));                                \
      uint4 e2 = *((const uint4*)(hp + 8));                                \
      uint4 e3 = *((const uint4*)(hp + 12));                               \
      uint4 e4 = *((const uint4*)(hp + 16));                               \
      uint4 e5 = *((const uint4*)(hp + 20));                               \
      uint2 e6 = *((const uint2*)(hp + 24));                               \
      float a0, a1, a2, a3;                                                \
      a0 = fdot2(wt[0], bc_h2(e0.x), 0.f);                                 \
      a1 = fdot2(wt[1], bc_h2(e0.y), 0.f);                                 \
      a2 = fdot2(wt[2], bc_h2(e0.z), 0.f);                                 \
      a3 = fdot2(wt[3], bc_h2(e0.w), 0.f);                                 \
      EDOT(4, e1.x)  EDOT(5, e1.y)  EDOT(6, e1.z)  EDOT(7, e1.w)           \
      EDOT(8, e2.x)  EDOT(9, e2.y)  EDOT(10, e2.z) EDOT(11, e2.w)          \
      EDOT(12, e3.x) EDOT(13, e3.y) EDOT(14, e3.z) EDOT(15, e3.w)          \
      EDOT(16, e4.x) EDOT(17, e4.y) EDOT(18, e4.z) EDOT(19, e4.w)          \
      EDOT(20, e5.x) EDOT(21, e5.y) EDOT(22, e5.z) EDOT(23, e5.w)          \
      EDOT(24, e6.x) EDOT(25, e6.y)                                        \
      float ss = (a0 + a1) + (a2 + a3);                                    \
      float tot = qadd<177>(ss);                                           \
      if (hf == 0) *emp = tot + bt;                                        \
      emp += estep;                                                        \
    }                                                                      \
    lds_barrier();                                                         \
  }

  __syncthreads();  // xlds-pad / hls init complete

  for (int T = 0; T < NTILE; ++T) {
    // ---- write prefetched x regs to xlds ----
    if (tp_act) {
      unsigned int* xr = xlds + tprow * 68 + 4 * tps;
      if (tps < 12) {
        uint4 u;
        u.x = pk(xa.x, xa.y); u.y = pk(xa.z, xa.w);
        u.z = pk(xb.x, xb.y); u.w = pk(xb.z, xb.w);
        *(uint4*)xr = u;
      } else {
        xr[0] = pk(xa.x, xa.y);
        xr[1] = pk(xa.z, xa.w);
      }
    }
    __syncthreads();

    // ---- BURST ----
    {
      v8h af[2][4];
#pragma unroll
      for (int rg = 0; rg < 2; ++rg)
#pragma unroll
        for (int f = 0; f < 4; ++f)
          af[rg][f] = __builtin_bit_cast(v8h,
              *(const uint4*)(xlds + (rg * 16 + l16) * 68 + f * 16 + quad * 4));

      // kick off next tile's x prefetch (stays in flight through the scan)
      if (tp_act && T + 1 < NTILE) {
        int ii = (T + 1) * TS + tprow;
        int tt = dir ? (TT - 1 - ii) : ii;
        int tk = tok[b * TT + tt];
        const float* xp = emb + (size_t)tk * DD + 8 * tps;
        xa = *(const float4*)xp;
        if (tps < 12) xb = *(const float4*)(xp + 4);
      }

      __fp16* gout = (__fp16*)gin_lds;
#pragma unroll
      for (int ci = 0; ci < 4; ++ci) {
        if (ci >= ncol) break;
        const int p = pcol[ci];
#pragma unroll
        for (int rg = 0; rg < 2; ++rg) {
          v4f acc = {0.f, 0.f, 0.f, 0.f};
          acc = __builtin_amdgcn_mfma_f32_16x16x32_f16(af[rg][0], bfr[ci][0], acc, 0, 0, 0);
          acc = __builtin_amdgcn_mfma_f32_16x16x32_f16(af[rg][1], bfr[ci][1], acc, 0, 0, 0);
          acc = __builtin_amdgcn_mfma_f32_16x16x32_f16(af[rg][2], bfr[ci][2], acc, 0, 0, 0);
          acc = __builtin_amdgcn_mfma_f32_16x16x32_f16(af[rg][3], bfr[ci][3], acc, 0, 0, 0);
          const int rowb = rg * 16 + quad * 4;
#pragma unroll
          for (int r = 0; r < 4; ++r)
            gout[(rowb + r) * 400 + p] = (__fp16)acc[r];
        }
      }
    }
    __syncthreads();
    if (uact) { grow = 0; gnext = gin_lds[tid]; }

    // ---- TS scan steps ----
    SCAN_STEP(hls0, hls1, (T > 0))
    SCAN_STEP(hls1, hls0, true)
    for (int it = 1; it < TS / 2; ++it) {
      SCAN_STEP(hls0, hls1, true)
      SCAN_STEP(hls1, hls0, true)
    }
  }
#undef SCAN_STEP
#undef SDOT

  // epilogue: emission for the last h (in hls0)
  if (eact) {
    const unsigned int* hp = hls0 + eo;
    uint4 e0 = *((const uint4*)hp);
    uint4 e1 = *((const uint4*)(hp + 4));
    uint4 e2 = *((const uint4*)(hp + 8));
    uint4 e3 = *((const uint4*)(hp + 12));
    uint4 e4 = *((const uint4*)(hp + 16));
    uint4 e5 = *((const uint4*)(hp + 20));
    uint2 e6 = *((const uint2*)(hp + 24));
    float a0, a1, a2, a3;
    a0 = fdot2(wt[0], bc_h2(e0.x), 0.f);
    a1 = fdot2(wt[1], bc_h2(e0.y), 0.f);
    a2 = fdot2(wt[2], bc_h2(e0.z), 0.f);
    a3 = fdot2(wt[3], bc_h2(e0.w), 0.f);
    EDOT(4, e1.x)  EDOT(5, e1.y)  EDOT(6, e1.z)  EDOT(7, e1.w)
    EDOT(8, e2.x)  EDOT(9, e2.y)  EDOT(10, e2.z) EDOT(11, e2.w)
    EDOT(12, e3.x) EDOT(13, e3.y) EDOT(14, e3.z) EDOT(15, e3.w)
    EDOT(16, e4.x) EDOT(17, e4.y) EDOT(18, e4.z) EDOT(19, e4.w)
    EDOT(20, e5.x) EDOT(21, e5.y) EDOT(22, e5.z) EDOT(23, e5.w)
    EDOT(24, e6.x) EDOT(25, e6.y)
    float ss = (a0 + a1) + (a2 + a3);
    float tot = qadd<177>(ss);
    if (hf == 0) {
      int ttp = dir ? 0 : (TT - 1);
      emo[((size_t)b * TT + ttp) * LL + l] = tot + bt;
    }
  }
#undef EDOT
}

// ---------------------------------------------------------------------------
// CRF all-in-one (v2 — best measured): block b = batch elem, 192 threads.
// Wave 0 = forward alpha, wave 1 = backward beta, wave 2 = gold.
// Per-step broadcast of A = 2^(a-sh) via per-wave LDS buffer (1 write +
// 7 b128 broadcast reads). atomicAdd(out, logZ - gold); d_out pre-zeroed.
// ---------------------------------------------------------------------------
__global__ __launch_bounds__(192) void crf_all2(
    const float* __restrict__ em_f, const float* __restrict__ em_b,
    const int* __restrict__ tags, const int* __restrict__ lengths,
    const float* __restrict__ trans,
    const float* __restrict__ startt, const float* __restrict__ endt,
    float* __restrict__ out)
{
  const int tid = threadIdx.x;
  const int b   = blockIdx.x;
  const int w   = tid >> 6;
  const int lane = tid & 63;

  __shared__ __align__(16) float As[2][32];
  __shared__ float abf[LL], abb[LL];
  __shared__ float gd;

  if (w < 2 && lane >= LL && lane < 32) As[w][lane] = 0.f;

  if (w < 2) {
    const int side = w;
    const int j = (lane < LL) ? lane : 0;
    const float* ef = em_f + (size_t)b * TT * LL;
    const float* eb = em_b + (size_t)b * TT * LL;
    float* Aw = As[side];
    const float4* Ap = (const float4*)Aw;

    float E[28];
#pragma unroll
    for (int i = 0; i < LL; ++i) {
      float tv = (side == 0 ? trans[i * LL + j] : trans[j * LL + i]);
      E[i] = fexp2(tv * F_LOG2E);
    }
    E[25] = 0.f; E[26] = 0.f; E[27] = 0.f;

#define LSE_STEP(vin, aout)                                                \
    {                                                                      \
      float sh = rfl(vin);                                                 \
      C += sh;                                                             \
      float A = fexp2((vin) - sh);                                         \
      if (lane < LL) Aw[lane] = A;                                         \
      wave_fence();                                                        \
      float4 q0 = Ap[0], q1 = Ap[1], q2 = Ap[2], q3 = Ap[3];               \
      float4 q4 = Ap[4], q5 = Ap[5], q6 = Ap[6];                           \
      float s0, s1, s2, s3;                                                \
      s0 = q0.x * E[0];  s1 = q0.y * E[1];                                 \
      s2 = q0.z * E[2];  s3 = q0.w * E[3];                                 \
      s0 = fmaf(q1.x, E[4], s0);  s1 = fmaf(q1.y, E[5], s1);               \
      s2 = fmaf(q1.z, E[6], s2);  s3 = fmaf(q1.w, E[7], s3);               \
      s0 = fmaf(q2.x, E[8], s0);  s1 = fmaf(q2.y, E[9], s1);               \
      s2 = fmaf(q2.z, E[10], s2); s3 = fmaf(q2.w, E[11], s3);              \
      s0 = fmaf(q3.x, E[12], s0); s1 = fmaf(q3.y, E[13], s1);              \
      s2 = fmaf(q3.z, E[14], s2); s3 = fmaf(q3.w, E[15], s3);              \
      s0 = fmaf(q4.x, E[16], s0); s1 = fmaf(q4.y, E[17], s1);              \
      s2 = fmaf(q4.z, E[18], s2); s3 = fmaf(q4.w, E[19], s3);              \
      s0 = fmaf(q5.x, E[20], s0); s1 = fmaf(q5.y, E[21], s1);              \
      s2 = fmaf(q5.z, E[22], s2); s3 = fmaf(q5.w, E[23], s3);              \
      s0 = fmaf(q6.x, E[24], s0); s1 = fmaf(q6.y, E[25], s1);              \
      s2 = fmaf(q6.z, E[26], s2); s3 = fmaf(q6.w, E[27], s3);              \
      aout = flog2((s0 + s1) + (s2 + s3));                                 \
    }

    float a, C = 0.f;
    if (side == 0) {
      a = (startt[j] + ef[j] + eb[j]) * F_LOG2E;
      float efA = ef[LL + j],     ebA = eb[LL + j];
      float efB = ef[2 * LL + j], ebB = eb[2 * LL + j];
      for (int t = 1; t < 256; ++t) {
        float em2 = (efA + ebA) * F_LOG2E;
        int tn = (t + 2 < 256) ? (t + 2) : 255;
        efA = efB; ebA = ebB;
        efB = ef[(size_t)tn * LL + j];
        ebB = eb[(size_t)tn * LL + j];
        float nx;
        LSE_STEP(a, nx)
        a = nx + em2;
      }
    } else {
      a = endt[j] * F_LOG2E;
      float efA = ef[(size_t)(TT - 1) * LL + j], ebA = eb[(size_t)(TT - 1) * LL + j];
      float efB = ef[(size_t)(TT - 2) * LL + j], ebB = eb[(size_t)(TT - 2) * LL + j];
      for (int stpi = 0; stpi < 256; ++stpi) {
        float em2 = (efA + ebA) * F_LOG2E;
        int t1n = (stpi + 2 < 256) ? (TT - 3 - stpi) : 256;
        efA = efB; ebA = ebB;
        efB = ef[(size_t)t1n * LL + j];
        ebB = eb[(size_t)t1n * LL + j];
        float v = a + em2;
        LSE_STEP(v, a)
      }
    }
#undef LSE_STEP
    if (lane < LL) {
      if (side == 0) abf[lane] = a + C;   // log2 domain
      else          abb[lane] = a + C;
    }
  } else {
    const int len = lengths[b];
    float acc = 0.f;
#pragma unroll
    for (int k = 0; k < 8; ++k) {
      int t = k * 64 + lane;
      int tg = tags[b * TT + t];
      size_t ei = ((size_t)b * TT + t) * LL + tg;
      float e = em_f[ei] + em_b[ei];
      float term;
      if (t == 0) term = startt[tg] + e;
      else        term = trans[tags[b * TT + t - 1] * LL + tg] + e;
      if (t == len - 1) term += endt[tg];
      if (t < len) acc += term;
    }
    for (int o = 32; o > 0; o >>= 1) acc += __shfl_down(acc, o);
    if (lane == 0) gd = acc;
  }
  __syncthreads();

  if (tid < 64) {
    float v = (tid < LL) ? (abf[tid] + abb[tid]) : -1e30f;
    float m = v;
    for (int o = 32; o > 0; o >>= 1) m = fmaxf(m, __shfl_down(m, o));
    m = rfl(m);
    float e = (tid < LL) ? fexp2(v - m) : 0.f;
    for (int o = 32; o > 0; o >>= 1) e += __shfl_down(e, o);
    if (tid == 0)
      atomicAdd(out, (m + flog2(e)) * F_LN2 - gd);
  }
}

extern "C" void kernel_launch(void* const* d_in, const int* in_sizes, int n_in,
                              void* d_out, int out_size, void* d_ws, size_t ws_size,
                              hipStream_t stream) {
  const int*   tok   = (const int*)d_in[0];
  const int*   tags  = (const int*)d_in[1];
  const int*   lens  = (const int*)d_in[2];
  const float* emb   = (const float*)d_in[3];
  const float* wif   = (const float*)d_in[4];
  const float* whf   = (const float*)d_in[5];
  const float* bif   = (const float*)d_in[6];
  const float* bhf   = (const float*)d_in[7];
  const float* wib   = (const float*)d_in[8];
  const float* whb   = (const float*)d_in[9];
  const float* bib   = (const float*)d_in[10];
  const float* bhb   = (const float*)d_in[11];
  const float* wtag  = (const float*)d_in[12];
  const float* btag  = (const float*)d_in[13];
  const float* trans = (const float*)d_in[14];
  const float* st    = (const float*)d_in[15];
  const float* en    = (const float*)d_in[16];

  char* wsb = (char*)d_ws;
  float* em_f = (float*)wsb;                                   //  6,553,600 B
  float* em_b = (float*)(wsb + 6553600);                       //  6,553,600 B

  hipMemsetAsync(d_out, 0, sizeof(float), stream);

  lstm_fused3<<<256, 512, 0, stream>>>(tok, emb, wif, wib, bif, bhf, bib, bhb,
                                       whf, whb, wtag, btag, em_f, em_b);
  crf_all2<<<128, 192, 0, stream>>>(em_f, em_b, tags, lens, trans, st, en,
                                    (float*)d_out);
}